// Round 16
// baseline (175.889 us; speedup 1.0000x reference)
//
#include <hip/hip_runtime.h>
#include <hip/hip_bf16.h>

#define DEV __device__ __forceinline__

typedef __bf16 bf16x8 __attribute__((ext_vector_type(8)));
typedef float f32x4 __attribute__((ext_vector_type(4)));
typedef float f32x16 __attribute__((ext_vector_type(16)));
using u16 = unsigned short;
using u32 = unsigned int;

static constexpr int S = 2048;
static constexpr int D = 1024;
static constexpr float SCQ = 0.125f * 1.44269504088896340736f;  // 1/sqrt(64)*log2(e)

DEV u16 f2bf(float f) {  // RNE
  unsigned u = __builtin_bit_cast(unsigned, f);
  u += 0x7fffu + ((u >> 16) & 1u);
  return (u16)(u >> 16);
}
DEV u16 f2bfr(float f) {  // round-half-up (cheap)
  return (u16)((__builtin_bit_cast(u32, f) + 0x8000u) >> 16);
}
// two f32 -> packed bf16x2, round-half-up: 2 int adds + one v_perm
DEV u32 pk2(float a, float b) {
  u32 ua = __builtin_bit_cast(u32, a) + 0x8000u;
  u32 ub = __builtin_bit_cast(u32, b) + 0x8000u;
  return __builtin_amdgcn_perm(ub, ua, 0x07060302);  // {lo: a, hi: b}
}

// async global->LDS DMA, 16B per lane. LDS dest is wave-uniform base + lane*16
// (dest must be linear in lane order; global src is per-lane).
DEV void gl16(const u16* __restrict__ g, u16* l) {
  __builtin_amdgcn_global_load_lds((const __attribute__((address_space(1))) u32*)g,
                                   (__attribute__((address_space(3))) u32*)l, 16, 0, 0);
}

// ---- merged prep: x pack + W_qkv transpose + W_out transpose (one dispatch) ----
__global__ __launch_bounds__(256) void k_prep(const float* __restrict__ x, u16* __restrict__ Xb,
                                              const float* __restrict__ Wqkv, u16* __restrict__ WqkvT,
                                              const float* __restrict__ Wout, u16* __restrict__ WoutT) {
  __shared__ float t[32][33];
  const int bid = blockIdx.x;
  const int tid = threadIdx.x;
  if (bid < 4096) {  // pack x: 4096 blocks x 256 threads x 1 float4
    const int i = bid * 256 + tid;
    const float4 v = reinterpret_cast<const float4*>(x)[i];
    ushort4 o;
    o.x = f2bf(v.x); o.y = f2bf(v.y); o.z = f2bf(v.z); o.w = f2bf(v.w);
    reinterpret_cast<ushort4*>(Xb)[i] = o;
    return;
  }
  const float* in;
  u16* out;
  int R, C, bx, by;
  if (bid < 4096 + 3072) {  // W_qkv [1024][3072] -> [3072][1024]
    const int b = bid - 4096;
    in = Wqkv; out = WqkvT; R = 1024; C = 3072;
    bx = b % 96; by = b / 96;
  } else {  // W_out [1024][1024] -> [1024][1024]^T
    const int b = bid - 7168;
    in = Wout; out = WoutT; R = 1024; C = 1024;
    bx = b & 31; by = b >> 5;
  }
  const int tx = tid & 31, ty = tid >> 5;
  const int c0 = bx * 32, r0 = by * 32;
  for (int i = ty; i < 32; i += 8)
    t[i][tx] = in[(size_t)(r0 + i) * C + c0 + tx];
  __syncthreads();
  for (int i = ty; i < 32; i += 8)
    out[(size_t)(c0 + i) * R + r0 + tx] = f2bf(t[tx][i]);
}

// ---- 128x128 bf16 GEMM (QKV): T4 counted-vmcnt pipeline (triple-buffer,
// 2-tiles-ahead). R14: 54.0 -> <49 us. ----
__global__ __launch_bounds__(256, 3) void k_gemm0(const u16* __restrict__ A, const u16* __restrict__ Bt,
                                                  const float* __restrict__ bias, int M, int N, int K,
                                                  u16* __restrict__ Qb, u16* __restrict__ Kb,
                                                  u16* __restrict__ Vt) {
  constexpr int TN = 128, NJ = 4;
  constexpr int BSZ = 128 * 32 * 2;  // 8192 per operand per buf
  __shared__ __align__(16) char smem[3 * 2 * BSZ];  // 49152
  auto As = reinterpret_cast<u16(*)[128][32]>(smem);
  auto Bs = reinterpret_cast<u16(*)[128][32]>(smem + 3 * BSZ);
  auto LT = reinterpret_cast<u16(*)[136]>(smem);  // epilogue-only overlay, 64x136x2 = 17408B
  const int tid = threadIdx.x;
  const int lane = tid & 63, wave = tid >> 6;
  const int l15 = lane & 15, quad = lane >> 4;
  // XCD swizzle: nwg = 24*32 = 768, chunk = 96 (4 M-rows of 24)
  const int bid0 = blockIdx.x + 24 * blockIdx.y;
  const int bid = (bid0 & 7) * 96 + (bid0 >> 3);
  const int m0 = (bid / 24) * 128, n0 = (bid % 24) * TN;
  const int wm = (wave >> 1) * 64, wn = (wave & 1) * (TN / 2);
  const int lr = lane >> 2;  // 0..15: row within a 16-row staging group
  const int lcs = ((((lane & 3) - (lane >> 3)) & 3)) * 8;   // inverse-swizzled source col
  const int sq = ((quad + (l15 >> 1)) & 3) * 8;             // swizzled read col

  f32x4 acc[4][NJ];
#pragma unroll
  for (int i = 0; i < 4; i++)
#pragma unroll
    for (int j = 0; j < NJ; j++) acc[i][j] = (f32x4){0.f, 0.f, 0.f, 0.f};

  const u16* Aw0 = &A[(size_t)(m0 + wave * 32 + lr) * K + lcs];
  const u16* Aw1 = &A[(size_t)(m0 + wave * 32 + 16 + lr) * K + lcs];
  const u16* Bw0 = &Bt[(size_t)(n0 + wave * 32 + lr) * K + lcs];
  const u16* Bw1 = &Bt[(size_t)(n0 + wave * 32 + 16 + lr) * K + lcs];

  // prologue: tiles 0,1 -> bufs 0,1 (4 gl16 each per wave)
  gl16(Aw0, &As[0][wave * 32][0]);
  gl16(Aw1, &As[0][wave * 32 + 16][0]);
  gl16(Bw0, &Bs[0][wave * 32][0]);
  gl16(Bw1, &Bs[0][wave * 32 + 16][0]);
  gl16(Aw0 + 32, &As[1][wave * 32][0]);
  gl16(Aw1 + 32, &As[1][wave * 32 + 16][0]);
  gl16(Bw0 + 32, &Bs[1][wave * 32][0]);
  gl16(Bw1 + 32, &Bs[1][wave * 32 + 16][0]);

  int cur = 0, nx2 = 2;
  for (int kk = 0; kk < K; kk += 32) {
    // vmcnt ledger: steady entry = 8 outstanding (tiles k, k+1). Wait ->4 keeps
    // tile k+1 in flight. Last iter: only tile k left (4) -> full drain.
    if (kk + 32 < K) asm volatile("s_waitcnt vmcnt(4)" ::: "memory");
    else             asm volatile("s_waitcnt vmcnt(0)" ::: "memory");
    __builtin_amdgcn_s_barrier();
    __builtin_amdgcn_sched_barrier(0);
    if (kk + 64 < K) {  // issue tile k+2 -> buf[nx2] (last read iter k-1)
      gl16(Aw0 + kk + 64, &As[nx2][wave * 32][0]);
      gl16(Aw1 + kk + 64, &As[nx2][wave * 32 + 16][0]);
      gl16(Bw0 + kk + 64, &Bs[nx2][wave * 32][0]);
      gl16(Bw1 + kk + 64, &Bs[nx2][wave * 32 + 16][0]);
    }
    bf16x8 af[4], bfv[NJ];
#pragma unroll
    for (int i = 0; i < 4; i++)
      af[i] = *reinterpret_cast<const bf16x8*>(&As[cur][wm + i * 16 + l15][sq]);
#pragma unroll
    for (int j = 0; j < NJ; j++)
      bfv[j] = *reinterpret_cast<const bf16x8*>(&Bs[cur][wn + j * 16 + l15][sq]);
#pragma unroll
    for (int i = 0; i < 4; i++)
#pragma unroll
      for (int j = 0; j < NJ; j++)
        acc[i][j] = __builtin_amdgcn_mfma_f32_16x16x32_bf16(af[i], bfv[j], acc[i][j], 0, 0, 0);
    cur = (cur == 2) ? 0 : cur + 1;
    nx2 = (nx2 == 2) ? 0 : nx2 + 1;
  }

  if (n0 >= 2048) {
    // ---- V blocks: LDS transpose (LT overlays staging bufs) -> stores along s ----
    const int b = m0 >> 11, sbase = m0 & 2047;
#pragma unroll
    for (int p = 0; p < 2; p++) {
      __syncthreads();
      if ((wave & 1) == p) {
#pragma unroll
        for (int j = 0; j < NJ; j++) {
          const int n = n0 + wn + j * 16 + l15;
          const float vb = bias[n];
#pragma unroll
          for (int i = 0; i < 4; i++) {
            uint2 pw;
            pw.x = pk2(acc[i][j][0] + vb, acc[i][j][1] + vb);
            pw.y = pk2(acc[i][j][2] + vb, acc[i][j][3] + vb);
            *reinterpret_cast<uint2*>(&LT[j * 16 + l15][wm + i * 16 + quad * 4]) = pw;
          }
        }
      }
      __syncthreads();
      const int h = ((n0 - 2048) >> 6) + p;
      const int bh = b * 16 + h;
      const int nl = tid >> 2, cc = (tid & 3) * 32;
      u16* dst = &Vt[((size_t)bh * 64 + nl) * S + sbase + cc];
#pragma unroll
      for (int k = 0; k < 4; k++)
        reinterpret_cast<uint4*>(dst)[k] = *reinterpret_cast<const uint4*>(&LT[nl][cc + k * 8]);
    }
  } else {
    // ---- Q/K blocks: direct stores (coalesced over l15) ----
#pragma unroll
    for (int i = 0; i < 4; i++) {
#pragma unroll
      for (int j = 0; j < NJ; j++) {
#pragma unroll
        for (int r = 0; r < 4; r++) {
          const int m = m0 + wm + i * 16 + quad * 4 + r;
          const int n = n0 + wn + j * 16 + l15;
          const float v = acc[i][j][r] + bias[n];
          const int h = (n >> 6) & 15, dh = n & 63;
          const int b = m >> 11, s = m & 2047;
          const int bh = b * 16 + h;
          if (n < 1024) Qb[((size_t)bh * S + s) * 64 + dh] = f2bfr(v * SCQ);
          else          Kb[((size_t)bh * S + s) * 64 + dh] = f2bfr(v);
        }
      }
    }
  }
}

// ---- out-proj GEMM: 128x64 tile, BK=32, T4 counted-vmcnt triple-buffer at
// 4 blocks/CU. R15 analysis: gemm2 ~45-50us for 8.6 GFLOP (~190 TF) with 2
// blocks/CU (72KB LDS) — TLP-starved behind the pipeline. BK=32 shrinks bufs
// to (128+64)x32x2 = 12KB, x3 = 36.9KB -> 4 blocks/CU, doubling resident
// waves while keeping the 2-ahead counted-vmcnt pipeline (R14-validated).
// Staging/read swizzle identical to gemm0 (64B rows). vmcnt ledger: 3 gl16/
// tile/wave -> steady entry 6, wait vmcnt(3); tail iter30 wait(3), iter31 wait(0).
__global__ __launch_bounds__(256, 4) void k_gemm2(const u16* __restrict__ A, const u16* __restrict__ Bt,
                                                  const float* __restrict__ bias, float* __restrict__ outF) {
  constexpr int K = 1024, N = 1024;
  constexpr int ABSZ = 128 * 32 * 2;  // 8192
  constexpr int BBSZ = 64 * 32 * 2;   // 4096
  __shared__ __align__(16) char smem[3 * (ABSZ + BBSZ)];  // 36864
  auto As = reinterpret_cast<u16(*)[128][32]>(smem);
  auto Bs = reinterpret_cast<u16(*)[64][32]>(smem + 3 * ABSZ);
  const int tid = threadIdx.x;
  const int lane = tid & 63, wave = tid >> 6;
  const int l15 = lane & 15, quad = lane >> 4;
  // XCD swizzle: nwg = 16*32 = 512, chunk = 64
  const int bid0 = blockIdx.x + 16 * blockIdx.y;
  const int bid = (bid0 & 7) * 64 + (bid0 >> 3);
  const int m0 = (bid >> 4) * 128, n0 = (bid & 15) * 64;
  const int wm = (wave >> 1) * 64, wn = (wave & 1) * 32;
  const int lr = lane >> 2;  // 0..15: row within a 16-row staging group
  const int lcs = ((((lane & 3) - (lane >> 3)) & 3)) * 8;   // inverse-swizzled source col
  const int sq = ((quad + (l15 >> 1)) & 3) * 8;             // swizzled read col

  f32x4 acc[4][2];
#pragma unroll
  for (int i = 0; i < 4; i++)
#pragma unroll
    for (int j = 0; j < 2; j++) acc[i][j] = (f32x4){0.f, 0.f, 0.f, 0.f};

  // staging: A wave w owns rows [w*32, w*32+32) (2 gl16); B rows [w*16, w*16+16) (1 gl16)
  const u16* Aw0 = &A[(size_t)(m0 + wave * 32 + lr) * K + lcs];
  const u16* Aw1 = &A[(size_t)(m0 + wave * 32 + 16 + lr) * K + lcs];
  const u16* Bw0 = &Bt[(size_t)(n0 + wave * 16 + lr) * K + lcs];

  // prologue: tiles 0,1 -> bufs 0,1 (3 gl16 each per wave)
  gl16(Aw0, &As[0][wave * 32][0]);
  gl16(Aw1, &As[0][wave * 32 + 16][0]);
  gl16(Bw0, &Bs[0][wave * 16][0]);
  gl16(Aw0 + 32, &As[1][wave * 32][0]);
  gl16(Aw1 + 32, &As[1][wave * 32 + 16][0]);
  gl16(Bw0 + 32, &Bs[1][wave * 16][0]);

  int cur = 0, nx2 = 2;
  for (int kk = 0; kk < K; kk += 32) {
    if (kk + 32 < K) asm volatile("s_waitcnt vmcnt(3)" ::: "memory");
    else             asm volatile("s_waitcnt vmcnt(0)" ::: "memory");
    __builtin_amdgcn_s_barrier();
    __builtin_amdgcn_sched_barrier(0);
    if (kk + 64 < K) {  // issue tile k+2 -> buf[nx2] (last read iter k-1)
      gl16(Aw0 + kk + 64, &As[nx2][wave * 32][0]);
      gl16(Aw1 + kk + 64, &As[nx2][wave * 32 + 16][0]);
      gl16(Bw0 + kk + 64, &Bs[nx2][wave * 16][0]);
    }
    bf16x8 af[4], bfv[2];
#pragma unroll
    for (int i = 0; i < 4; i++)
      af[i] = *reinterpret_cast<const bf16x8*>(&As[cur][wm + i * 16 + l15][sq]);
#pragma unroll
    for (int j = 0; j < 2; j++)
      bfv[j] = *reinterpret_cast<const bf16x8*>(&Bs[cur][wn + j * 16 + l15][sq]);
#pragma unroll
    for (int i = 0; i < 4; i++)
#pragma unroll
      for (int j = 0; j < 2; j++)
        acc[i][j] = __builtin_amdgcn_mfma_f32_16x16x32_bf16(af[i], bfv[j], acc[i][j], 0, 0, 0);
    cur = (cur == 2) ? 0 : cur + 1;
    nx2 = (nx2 == 2) ? 0 : nx2 + 1;
  }

#pragma unroll
  for (int i = 0; i < 4; i++)
#pragma unroll
    for (int j = 0; j < 2; j++)
#pragma unroll
      for (int r = 0; r < 4; r++) {
        const int m = m0 + wm + i * 16 + quad * 4 + r;
        const int n = n0 + wn + j * 16 + l15;
        outF[(size_t)m * N + n] = acc[i][j][r] + bias[n];
      }
}

// ---- attn helpers: produce (QK) and consume (softmax+PV) — inlined, all
// register state passed by reference (named f32x16s; arrays spill, R6/R11) ----
DEV void qk_produce(f32x16& z0, f32x16& z1, const u16 (*Ksb)[72],
                    const bf16x8* qf, int l31, int hi) {
#pragma unroll
  for (int r = 0; r < 16; r++) { z0[r] = 0.f; z1[r] = 0.f; }
  __builtin_amdgcn_s_setprio(1);
#pragma unroll
  for (int f = 0; f < 4; f++) {
    const bf16x8 a0 = *reinterpret_cast<const bf16x8*>(&Ksb[l31][f * 16 + hi * 8]);
    const bf16x8 a1 = *reinterpret_cast<const bf16x8*>(&Ksb[32 + l31][f * 16 + hi * 8]);
    z0 = __builtin_amdgcn_mfma_f32_32x32x16_bf16(a0, qf[f], z0, 0, 0, 0);
    z1 = __builtin_amdgcn_mfma_f32_32x32x16_bf16(a1, qf[f], z1, 0, 0, 0);
  }
  __builtin_amdgcn_s_setprio(0);
}

DEV void pv_half(const f32x16& z, int f0, const u16 (*Vsb)[72], int l31, int hi,
                 f32x16& o0, f32x16& o1) {
#pragma unroll
  for (int s = 0; s < 2; s++) {
    u32 w0 = pk2(z[s * 8 + 0], z[s * 8 + 1]);
    u32 w2 = pk2(z[s * 8 + 4], z[s * 8 + 5]);
    asm("v_permlane32_swap_b32 %0, %1" : "+v"(w0), "+v"(w2));
    u32 w1 = pk2(z[s * 8 + 2], z[s * 8 + 3]);
    u32 w3 = pk2(z[s * 8 + 6], z[s * 8 + 7]);
    asm("v_permlane32_swap_b32 %0, %1" : "+v"(w1), "+v"(w3));
    uint4 wv;
    wv.x = w0; wv.y = w1; wv.z = w2; wv.w = w3;
    const bf16x8 bp = __builtin_bit_cast(bf16x8, wv);
    const int f = f0 + s;
    const bf16x8 av0 = *reinterpret_cast<const bf16x8*>(&Vsb[l31][f * 16 + hi * 8]);
    const bf16x8 av1 = *reinterpret_cast<const bf16x8*>(&Vsb[32 + l31][f * 16 + hi * 8]);
    o0 = __builtin_amdgcn_mfma_f32_32x32x16_bf16(av0, bp, o0, 0, 0, 0);
    o1 = __builtin_amdgcn_mfma_f32_32x32x16_bf16(av1, bp, o1, 0, 0, 0);
  }
}

DEV void sm_pv(f32x16& z0, f32x16& z1, const u16 (*Vsb)[72], int l31, int hi,
               float& li, f32x16& o0, f32x16& o1) {
  float s0 = 0.f, s1 = 0.f, s2 = 0.f, s3 = 0.f;
#pragma unroll
  for (int r = 0; r < 16; r++) {
    const float p0 = __builtin_amdgcn_exp2f(z0[r]);
    const float p1 = __builtin_amdgcn_exp2f(z1[r]);
    z0[r] = p0; z1[r] = p1;
    if ((r & 3) == 0) { s0 += p0; s0 += p1; }
    else if ((r & 3) == 1) { s1 += p0; s1 += p1; }
    else if ((r & 3) == 2) { s2 += p0; s2 += p1; }
    else { s3 += p0; s3 += p1; }
  }
  li += (s0 + s1) + (s2 + s3);
  __builtin_amdgcn_s_setprio(1);
  pv_half(z0, 0, Vsb, l31, hi, o0, o1);
  pv_half(z1, 2, Vsb, l31, hi, o0, o1);
  __builtin_amdgcn_s_setprio(0);
}

// ---- flash attention: QBLK=128, 4 waves. T15 deferred softmax (R15: 49.4->46.7).
// V triple-buffered, K double-buffered. XCD swizzle, T5, T12. ----
__global__ __launch_bounds__(256, 2) void k_attn(const u16* __restrict__ Qb,
                                                 const u16* __restrict__ Kb,
                                                 const u16* __restrict__ Vt,
                                                 u16* __restrict__ attnB) {
  __shared__ u16 Ks[2][64][72];  // [buf][key][dh]       18.4KB
  __shared__ u16 Vs[3][64][72];  // [buf][dh][key_local] 27.6KB
  __shared__ u16 Pl[4][32][72];  // epilogue-only (O staging) 18.4KB
  const int tid = threadIdx.x;
  const int lane = tid & 63, wave = tid >> 6;
  const int l31 = lane & 31, hi = lane >> 5;
  // XCD swizzle: nwg = 512, chunk = 64 (4 bh of 16 q-blocks per XCD)
  const int bid0 = blockIdx.x + 16 * blockIdx.y;
  const int bid = (bid0 & 7) * 64 + (bid0 >> 3);
  const int bh = bid >> 4;
  const int q0 = (bid & 15) * 128;
  const u16* Qh = Qb + (size_t)bh * S * 64;
  const u16* Kh = Kb + (size_t)bh * S * 64;
  const u16* Vh = Vt + (size_t)bh * 64 * S;
  const int qrow = q0 + wave * 32 + l31;
  bf16x8 qf[4];  // Q (pre-scaled by SCQ) as B-operand: n = lane&31 = q
#pragma unroll
  for (int f = 0; f < 4; f++)
    qf[f] = *reinterpret_cast<const bf16x8*>(&Qh[(size_t)qrow * 64 + f * 16 + hi * 8]);

  const int r0 = tid >> 3, c0 = (tid & 7) * 8;  // staging: 8 lanes x 16B per 128B row

  float li = 0.f;
  f32x16 o0, o1;  // O d-tiles: d = dt*32 + (reg&3)+8*(reg>>2)+4*hi
#pragma unroll
  for (int r = 0; r < 16; r++) { o0[r] = 0.f; o1[r] = 0.f; }
  f32x16 zE0, zE1, zO0, zO1;  // even/odd-iter score sets (named; no arrays)

  // prologue: tile 0 -> regs
  uint4 pk0 = *reinterpret_cast<const uint4*>(&Kh[(size_t)r0 * 64 + c0]);
  uint4 pk1 = *reinterpret_cast<const uint4*>(&Kh[(size_t)(r0 + 32) * 64 + c0]);
  uint4 pv0 = *reinterpret_cast<const uint4*>(&Vh[(size_t)r0 * S + c0]);
  uint4 pv1 = *reinterpret_cast<const uint4*>(&Vh[(size_t)(r0 + 32) * S + c0]);

  constexpr int NT = S / 64;  // 32 (even)

#define ATTN_STEP(KB, ZC0, ZC1, ZP0, ZP1, DO_CONS)                                \
  {                                                                               \
    const int cur_ = (KB) & 1, vb_ = (KB) % 3;                                    \
    *reinterpret_cast<uint4*>(&Ks[cur_][r0][c0]) = pk0;                           \
    *reinterpret_cast<uint4*>(&Ks[cur_][r0 + 32][c0]) = pk1;                      \
    *reinterpret_cast<uint4*>(&Vs[vb_][r0][c0]) = pv0;                            \
    *reinterpret_cast<uint4*>(&Vs[vb_][r0 + 32][c0]) = pv1;                       \
    if ((KB) + 1 < NT) {                                                          \
      const u16* Kn_ = Kh + (size_t)((KB) + 1) * 64 * 64;                         \
      const u16* Vn_ = Vh + (size_t)((KB) + 1) * 64;                              \
      pk0 = *reinterpret_cast<const uint4*>(&Kn_[(size_t)r0 * 64 + c0]);          \
      pk1 = *reinterpret_cast<const uint4*>(&Kn_[(size_t)(r0 + 32) * 64 + c0]);   \
      pv0 = *reinterpret_cast<const uint4*>(&Vn_[(size_t)r0 * S + c0]);           \
      pv1 = *reinterpret_cast<const uint4*>(&Vn_[(size_t)(r0 + 32) * S + c0]);    \
    }                                                                             \
    __syncthreads();                                                              \
    qk_produce(ZC0, ZC1, Ks[cur_], qf, l31, hi);                                  \
    if (DO_CONS) sm_pv(ZP0, ZP1, Vs[((KB) + 2) % 3], l31, hi, li, o0, o1);        \
  }

  for (int p = 0; p < NT / 2; p++) {
    ATTN_STEP(2 * p,     zE0, zE1, zO0, zO1, p > 0);
    ATTN_STEP(2 * p + 1, zO0, zO1, zE0, zE1, true);
  }
  // epilogue: consume last tile (NT-1, odd -> zO), V in buf (NT-1)%3
  sm_pv(zO0, zO1, Vs[(NT - 1) % 3], l31, hi, li, o0, o1);
#undef ATTN_STEP

  li += __shfl_xor(li, 32);
  const float inv = 1.f / li;
  // O -> Pl[q][d] (wave-private), then coalesced store
#pragma unroll
  for (int dt = 0; dt < 2; dt++) {
    const f32x16& od = dt ? o1 : o0;
#pragma unroll
    for (int g = 0; g < 4; g++) {
      uint2 ow;
      ow.x = pk2(od[g * 4 + 0] * inv, od[g * 4 + 1] * inv);
      ow.y = pk2(od[g * 4 + 2] * inv, od[g * 4 + 3] * inv);
      *reinterpret_cast<uint2*>(&Pl[wave][l31][dt * 32 + g * 8 + hi * 4]) = ow;
    }
  }
  const int b = bh >> 4, h = bh & 15;
  const int mbase = b * S + q0 + wave * 32;
  const int qr = lane >> 1, ch = (lane & 1) * 32;
  u16* dst = &attnB[(size_t)(mbase + qr) * D + h * 64 + ch];
#pragma unroll
  for (int c = 0; c < 4; c++)
    reinterpret_cast<uint4*>(dst)[c] = *reinterpret_cast<const uint4*>(&Pl[wave][qr][ch + c * 8]);
}

extern "C" void kernel_launch(void* const* d_in, const int* in_sizes, int n_in,
                              void* d_out, int out_size, void* d_ws, size_t ws_size,
                              hipStream_t stream) {
  const float* x = (const float*)d_in[0];
  const float* Wqkv = (const float*)d_in[1];
  const float* bqkv = (const float*)d_in[2];
  const float* Wout = (const float*)d_in[3];
  const float* bout = (const float*)d_in[4];
  float* out = (float*)d_out;

  char* p = (char*)d_ws;
  u16* WoutT = (u16*)p; p += (size_t)1024 * 1024 * 2;     // 2MB  (live thru gemm2)
  u16* attnB = (u16*)p; p += (size_t)4096 * 1024 * 2;     // 8MB  (live thru gemm2)
  u16* Xb = (u16*)p;    p += (size_t)4096 * 1024 * 2;     // 8MB  (dead after gemm0)
  u16* WqkvT = (u16*)p; p += (size_t)3072 * 1024 * 2;     // 6MB  (dead after gemm0)
  u16* Vt = (u16*)p;    p += (size_t)32 * 64 * 2048 * 2;  // 8MB  (dead after attn)
  u16* Qb = (u16*)p;    p += (size_t)32 * 2048 * 64 * 2;  // 8MB  (dead after attn)
  u16* Kb = (u16*)p;    p += (size_t)32 * 2048 * 64 * 2;  // 8MB  (dead after attn)

  k_prep<<<4096 + 3072 + 1024, 256, 0, stream>>>(x, Xb, Wqkv, WqkvT, Wout, WoutT);
  k_gemm0<<<dim3(3072 / 128, 4096 / 128), 256, 0, stream>>>(
      Xb, WqkvT, bqkv, 4096, 3072, 1024, Qb, Kb, Vt);
  k_attn<<<dim3(2048 / 128, 32), 256, 0, stream>>>(Qb, Kb, Vt, attnB);
  k_gemm2<<<dim3(1024 / 64, 4096 / 128), 256, 0, stream>>>(attnB, WoutT, bout, out);
}

// Round 17
// 169.586 us; speedup vs baseline: 1.0372x; 1.0372x over previous
//
#include <hip/hip_runtime.h>
#include <hip/hip_bf16.h>

#define DEV __device__ __forceinline__

typedef __bf16 bf16x8 __attribute__((ext_vector_type(8)));
typedef float f32x4 __attribute__((ext_vector_type(4)));
typedef float f32x16 __attribute__((ext_vector_type(16)));
using u16 = unsigned short;
using u32 = unsigned int;

static constexpr int S = 2048;
static constexpr int D = 1024;
static constexpr float SCQ = 0.125f * 1.44269504088896340736f;  // 1/sqrt(64)*log2(e)

DEV u16 f2bf(float f) {  // RNE
  unsigned u = __builtin_bit_cast(unsigned, f);
  u += 0x7fffu + ((u >> 16) & 1u);
  return (u16)(u >> 16);
}
DEV u16 f2bfr(float f) {  // round-half-up (cheap)
  return (u16)((__builtin_bit_cast(u32, f) + 0x8000u) >> 16);
}
// two f32 -> packed bf16x2, round-half-up: 2 int adds + one v_perm
DEV u32 pk2(float a, float b) {
  u32 ua = __builtin_bit_cast(u32, a) + 0x8000u;
  u32 ub = __builtin_bit_cast(u32, b) + 0x8000u;
  return __builtin_amdgcn_perm(ub, ua, 0x07060302);  // {lo: a, hi: b}
}

// async global->LDS DMA, 16B per lane. LDS dest is wave-uniform base + lane*16
// (dest must be linear in lane order; global src is per-lane).
DEV void gl16(const u16* __restrict__ g, u16* l) {
  __builtin_amdgcn_global_load_lds((const __attribute__((address_space(1))) u32*)g,
                                   (__attribute__((address_space(3))) u32*)l, 16, 0, 0);
}

// ---- merged prep: x pack + W_qkv transpose + W_out transpose (one dispatch) ----
__global__ __launch_bounds__(256) void k_prep(const float* __restrict__ x, u16* __restrict__ Xb,
                                              const float* __restrict__ Wqkv, u16* __restrict__ WqkvT,
                                              const float* __restrict__ Wout, u16* __restrict__ WoutT) {
  __shared__ float t[32][33];
  const int bid = blockIdx.x;
  const int tid = threadIdx.x;
  if (bid < 4096) {  // pack x: 4096 blocks x 256 threads x 1 float4
    const int i = bid * 256 + tid;
    const float4 v = reinterpret_cast<const float4*>(x)[i];
    ushort4 o;
    o.x = f2bf(v.x); o.y = f2bf(v.y); o.z = f2bf(v.z); o.w = f2bf(v.w);
    reinterpret_cast<ushort4*>(Xb)[i] = o;
    return;
  }
  const float* in;
  u16* out;
  int R, C, bx, by;
  if (bid < 4096 + 3072) {  // W_qkv [1024][3072] -> [3072][1024]
    const int b = bid - 4096;
    in = Wqkv; out = WqkvT; R = 1024; C = 3072;
    bx = b % 96; by = b / 96;
  } else {  // W_out [1024][1024] -> [1024][1024]^T
    const int b = bid - 7168;
    in = Wout; out = WoutT; R = 1024; C = 1024;
    bx = b & 31; by = b >> 5;
  }
  const int tx = tid & 31, ty = tid >> 5;
  const int c0 = bx * 32, r0 = by * 32;
  for (int i = ty; i < 32; i += 8)
    t[i][tx] = in[(size_t)(r0 + i) * C + c0 + tx];
  __syncthreads();
  for (int i = ty; i < 32; i += 8)
    out[(size_t)(c0 + i) * R + r0 + tx] = f2bf(t[tx][i]);
}

// ---- 128x128 bf16 GEMM (QKV): T4 counted-vmcnt pipeline (triple-buffer,
// 2-tiles-ahead). R14: 54.0 -> ~41-47 us. ----
__global__ __launch_bounds__(256, 3) void k_gemm0(const u16* __restrict__ A, const u16* __restrict__ Bt,
                                                  const float* __restrict__ bias, int M, int N, int K,
                                                  u16* __restrict__ Qb, u16* __restrict__ Kb,
                                                  u16* __restrict__ Vt) {
  constexpr int TN = 128, NJ = 4;
  constexpr int BSZ = 128 * 32 * 2;  // 8192 per operand per buf
  __shared__ __align__(16) char smem[3 * 2 * BSZ];  // 49152
  auto As = reinterpret_cast<u16(*)[128][32]>(smem);
  auto Bs = reinterpret_cast<u16(*)[128][32]>(smem + 3 * BSZ);
  auto LT = reinterpret_cast<u16(*)[136]>(smem);  // epilogue-only overlay, 64x136x2 = 17408B
  const int tid = threadIdx.x;
  const int lane = tid & 63, wave = tid >> 6;
  const int l15 = lane & 15, quad = lane >> 4;
  // XCD swizzle: nwg = 24*32 = 768, chunk = 96 (4 M-rows of 24)
  const int bid0 = blockIdx.x + 24 * blockIdx.y;
  const int bid = (bid0 & 7) * 96 + (bid0 >> 3);
  const int m0 = (bid / 24) * 128, n0 = (bid % 24) * TN;
  const int wm = (wave >> 1) * 64, wn = (wave & 1) * (TN / 2);
  const int lr = lane >> 2;  // 0..15: row within a 16-row staging group
  const int lcs = ((((lane & 3) - (lane >> 3)) & 3)) * 8;   // inverse-swizzled source col
  const int sq = ((quad + (l15 >> 1)) & 3) * 8;             // swizzled read col

  f32x4 acc[4][NJ];
#pragma unroll
  for (int i = 0; i < 4; i++)
#pragma unroll
    for (int j = 0; j < NJ; j++) acc[i][j] = (f32x4){0.f, 0.f, 0.f, 0.f};

  const u16* Aw0 = &A[(size_t)(m0 + wave * 32 + lr) * K + lcs];
  const u16* Aw1 = &A[(size_t)(m0 + wave * 32 + 16 + lr) * K + lcs];
  const u16* Bw0 = &Bt[(size_t)(n0 + wave * 32 + lr) * K + lcs];
  const u16* Bw1 = &Bt[(size_t)(n0 + wave * 32 + 16 + lr) * K + lcs];

  // prologue: tiles 0,1 -> bufs 0,1 (4 gl16 each per wave)
  gl16(Aw0, &As[0][wave * 32][0]);
  gl16(Aw1, &As[0][wave * 32 + 16][0]);
  gl16(Bw0, &Bs[0][wave * 32][0]);
  gl16(Bw1, &Bs[0][wave * 32 + 16][0]);
  gl16(Aw0 + 32, &As[1][wave * 32][0]);
  gl16(Aw1 + 32, &As[1][wave * 32 + 16][0]);
  gl16(Bw0 + 32, &Bs[1][wave * 32][0]);
  gl16(Bw1 + 32, &Bs[1][wave * 32 + 16][0]);

  int cur = 0, nx2 = 2;
  for (int kk = 0; kk < K; kk += 32) {
    // vmcnt ledger: steady entry = 8 outstanding (tiles k, k+1). Wait ->4 keeps
    // tile k+1 in flight. Last iter: only tile k left (4) -> full drain.
    if (kk + 32 < K) asm volatile("s_waitcnt vmcnt(4)" ::: "memory");
    else             asm volatile("s_waitcnt vmcnt(0)" ::: "memory");
    __builtin_amdgcn_s_barrier();
    __builtin_amdgcn_sched_barrier(0);
    if (kk + 64 < K) {  // issue tile k+2 -> buf[nx2] (last read iter k-1)
      gl16(Aw0 + kk + 64, &As[nx2][wave * 32][0]);
      gl16(Aw1 + kk + 64, &As[nx2][wave * 32 + 16][0]);
      gl16(Bw0 + kk + 64, &Bs[nx2][wave * 32][0]);
      gl16(Bw1 + kk + 64, &Bs[nx2][wave * 32 + 16][0]);
    }
    bf16x8 af[4], bfv[NJ];
#pragma unroll
    for (int i = 0; i < 4; i++)
      af[i] = *reinterpret_cast<const bf16x8*>(&As[cur][wm + i * 16 + l15][sq]);
#pragma unroll
    for (int j = 0; j < NJ; j++)
      bfv[j] = *reinterpret_cast<const bf16x8*>(&Bs[cur][wn + j * 16 + l15][sq]);
#pragma unroll
    for (int i = 0; i < 4; i++)
#pragma unroll
      for (int j = 0; j < NJ; j++)
        acc[i][j] = __builtin_amdgcn_mfma_f32_16x16x32_bf16(af[i], bfv[j], acc[i][j], 0, 0, 0);
    cur = (cur == 2) ? 0 : cur + 1;
    nx2 = (nx2 == 2) ? 0 : nx2 + 1;
  }

  if (n0 >= 2048) {
    // ---- V blocks: LDS transpose (LT overlays staging bufs) -> stores along s ----
    const int b = m0 >> 11, sbase = m0 & 2047;
#pragma unroll
    for (int p = 0; p < 2; p++) {
      __syncthreads();
      if ((wave & 1) == p) {
#pragma unroll
        for (int j = 0; j < NJ; j++) {
          const int n = n0 + wn + j * 16 + l15;
          const float vb = bias[n];
#pragma unroll
          for (int i = 0; i < 4; i++) {
            uint2 pw;
            pw.x = pk2(acc[i][j][0] + vb, acc[i][j][1] + vb);
            pw.y = pk2(acc[i][j][2] + vb, acc[i][j][3] + vb);
            *reinterpret_cast<uint2*>(&LT[j * 16 + l15][wm + i * 16 + quad * 4]) = pw;
          }
        }
      }
      __syncthreads();
      const int h = ((n0 - 2048) >> 6) + p;
      const int bh = b * 16 + h;
      const int nl = tid >> 2, cc = (tid & 3) * 32;
      u16* dst = &Vt[((size_t)bh * 64 + nl) * S + sbase + cc];
#pragma unroll
      for (int k = 0; k < 4; k++)
        reinterpret_cast<uint4*>(dst)[k] = *reinterpret_cast<const uint4*>(&LT[nl][cc + k * 8]);
    }
  } else {
    // ---- Q/K blocks: direct stores (coalesced over l15) ----
#pragma unroll
    for (int i = 0; i < 4; i++) {
#pragma unroll
      for (int j = 0; j < NJ; j++) {
#pragma unroll
        for (int r = 0; r < 4; r++) {
          const int m = m0 + wm + i * 16 + quad * 4 + r;
          const int n = n0 + wn + j * 16 + l15;
          const float v = acc[i][j][r] + bias[n];
          const int h = (n >> 6) & 15, dh = n & 63;
          const int b = m >> 11, s = m & 2047;
          const int bh = b * 16 + h;
          if (n < 1024) Qb[((size_t)bh * S + s) * 64 + dh] = f2bfr(v * SCQ);
          else          Kb[((size_t)bh * S + s) * 64 + dh] = f2bfr(v);
        }
      }
    }
  }
}

// ---- out-proj GEMM: 128x64 tile, BK=64 + T4 counted-vmcnt triple-buffer.
// R15-proven shape (172.8 total). Alternatives measured WORSE: 64x64 (R5,
// occupancy-null), 128^2 split-K (R9, +14us partial traffic), BK=32 @4/CU
// (R16, +3us — halved work-per-barrier beats doubled TLP). Work-per-barrier
// dominates occupancy for this pipeline.
__global__ __launch_bounds__(256, 2) void k_gemm2(const u16* __restrict__ A, const u16* __restrict__ Bt,
                                                  const float* __restrict__ bias, float* __restrict__ outF) {
  constexpr int K = 1024, N = 1024;
  constexpr int ABSZ = 128 * 64 * 2;  // 16384
  constexpr int BBSZ = 64 * 64 * 2;   // 8192
  __shared__ __align__(16) char smem[3 * (ABSZ + BBSZ)];  // 73728
  auto As = reinterpret_cast<u16(*)[128][64]>(smem);
  auto Bs = reinterpret_cast<u16(*)[64][64]>(smem + 3 * ABSZ);
  const int tid = threadIdx.x;
  const int lane = tid & 63, wave = tid >> 6;
  const int l15 = lane & 15, quad = lane >> 4;
  // XCD swizzle: nwg = 16*32 = 512, chunk = 64
  const int bid0 = blockIdx.x + 16 * blockIdx.y;
  const int bid = (bid0 & 7) * 64 + (bid0 >> 3);
  const int m0 = (bid >> 4) * 128, n0 = (bid & 15) * 64;
  const int wm = (wave >> 1) * 64, wn = (wave & 1) * 32;
  const int srow = lane >> 3;                       // 0..7 row within 8-row chunk
  const int scol = ((lane & 7) ^ srow) * 8;         // inverse-swizzled source col

  f32x4 acc[4][2];
#pragma unroll
  for (int i = 0; i < 4; i++)
#pragma unroll
    for (int j = 0; j < 2; j++) acc[i][j] = (f32x4){0.f, 0.f, 0.f, 0.f};

  // staging pointers: A 16 chunks of 8 rows (4/wave), B 8 chunks (2/wave)
  const u16* Ap[4];
  const u16* Bp[2];
#pragma unroll
  for (int c = 0; c < 4; c++)
    Ap[c] = &A[(size_t)(m0 + (wave * 4 + c) * 8 + srow) * K + scol];
#pragma unroll
  for (int c = 0; c < 2; c++)
    Bp[c] = &Bt[(size_t)(n0 + (wave * 2 + c) * 8 + srow) * K + scol];

  // prologue: tiles 0,1 -> bufs 0,1 (6 gl16 each per wave)
#pragma unroll
  for (int c = 0; c < 4; c++) gl16(Ap[c], &As[0][(wave * 4 + c) * 8][0]);
#pragma unroll
  for (int c = 0; c < 2; c++) gl16(Bp[c], &Bs[0][(wave * 2 + c) * 8][0]);
#pragma unroll
  for (int c = 0; c < 4; c++) gl16(Ap[c] + 64, &As[1][(wave * 4 + c) * 8][0]);
#pragma unroll
  for (int c = 0; c < 2; c++) gl16(Bp[c] + 64, &Bs[1][(wave * 2 + c) * 8][0]);

  int cur = 0, nx2 = 2;
  for (int kk = 0; kk < K; kk += 64) {
    if (kk + 64 < K) asm volatile("s_waitcnt vmcnt(6)" ::: "memory");
    else             asm volatile("s_waitcnt vmcnt(0)" ::: "memory");
    __builtin_amdgcn_s_barrier();
    __builtin_amdgcn_sched_barrier(0);
    if (kk + 128 < K) {  // issue tile k+2 -> buf[nx2]
#pragma unroll
      for (int c = 0; c < 4; c++) gl16(Ap[c] + kk + 128, &As[nx2][(wave * 4 + c) * 8][0]);
#pragma unroll
      for (int c = 0; c < 2; c++) gl16(Bp[c] + kk + 128, &Bs[nx2][(wave * 2 + c) * 8][0]);
    }
#pragma unroll
    for (int ks = 0; ks < 2; ks++) {
      const int sc = ((ks * 4 + quad) ^ (l15 & 7)) * 8;  // swizzled read col
      bf16x8 af[4], bfv[2];
#pragma unroll
      for (int i = 0; i < 4; i++)
        af[i] = *reinterpret_cast<const bf16x8*>(&As[cur][wm + i * 16 + l15][sc]);
#pragma unroll
      for (int j = 0; j < 2; j++)
        bfv[j] = *reinterpret_cast<const bf16x8*>(&Bs[cur][wn + j * 16 + l15][sc]);
#pragma unroll
      for (int i = 0; i < 4; i++)
#pragma unroll
        for (int j = 0; j < 2; j++)
          acc[i][j] = __builtin_amdgcn_mfma_f32_16x16x32_bf16(af[i], bfv[j], acc[i][j], 0, 0, 0);
    }
    cur = (cur == 2) ? 0 : cur + 1;
    nx2 = (nx2 == 2) ? 0 : nx2 + 1;
  }

#pragma unroll
  for (int i = 0; i < 4; i++)
#pragma unroll
    for (int j = 0; j < 2; j++)
#pragma unroll
      for (int r = 0; r < 4; r++) {
        const int m = m0 + wm + i * 16 + quad * 4 + r;
        const int n = n0 + wn + j * 16 + l15;
        outF[(size_t)m * N + n] = acc[i][j][r] + bias[n];
      }
}

// ---- attn helpers: produce (QK) and consume (softmax+PV) — inlined, all
// register state passed by reference (named f32x16s; arrays spill, R6/R11) ----
DEV void qk_produce(f32x16& z0, f32x16& z1, const u16 (*Ksb)[72],
                    const bf16x8* qf, int l31, int hi) {
#pragma unroll
  for (int r = 0; r < 16; r++) { z0[r] = 0.f; z1[r] = 0.f; }
  __builtin_amdgcn_s_setprio(1);
#pragma unroll
  for (int f = 0; f < 4; f++) {
    const bf16x8 a0 = *reinterpret_cast<const bf16x8*>(&Ksb[l31][f * 16 + hi * 8]);
    const bf16x8 a1 = *reinterpret_cast<const bf16x8*>(&Ksb[32 + l31][f * 16 + hi * 8]);
    z0 = __builtin_amdgcn_mfma_f32_32x32x16_bf16(a0, qf[f], z0, 0, 0, 0);
    z1 = __builtin_amdgcn_mfma_f32_32x32x16_bf16(a1, qf[f], z1, 0, 0, 0);
  }
  __builtin_amdgcn_s_setprio(0);
}

DEV void pv_half(const f32x16& z, int f0, const u16 (*Vsb)[72], int l31, int hi,
                 f32x16& o0, f32x16& o1) {
#pragma unroll
  for (int s = 0; s < 2; s++) {
    u32 w0 = pk2(z[s * 8 + 0], z[s * 8 + 1]);
    u32 w2 = pk2(z[s * 8 + 4], z[s * 8 + 5]);
    asm("v_permlane32_swap_b32 %0, %1" : "+v"(w0), "+v"(w2));
    u32 w1 = pk2(z[s * 8 + 2], z[s * 8 + 3]);
    u32 w3 = pk2(z[s * 8 + 6], z[s * 8 + 7]);
    asm("v_permlane32_swap_b32 %0, %1" : "+v"(w1), "+v"(w3));
    uint4 wv;
    wv.x = w0; wv.y = w1; wv.z = w2; wv.w = w3;
    const bf16x8 bp = __builtin_bit_cast(bf16x8, wv);
    const int f = f0 + s;
    const bf16x8 av0 = *reinterpret_cast<const bf16x8*>(&Vsb[l31][f * 16 + hi * 8]);
    const bf16x8 av1 = *reinterpret_cast<const bf16x8*>(&Vsb[32 + l31][f * 16 + hi * 8]);
    o0 = __builtin_amdgcn_mfma_f32_32x32x16_bf16(av0, bp, o0, 0, 0, 0);
    o1 = __builtin_amdgcn_mfma_f32_32x32x16_bf16(av1, bp, o1, 0, 0, 0);
  }
}

DEV void sm_pv(f32x16& z0, f32x16& z1, const u16 (*Vsb)[72], int l31, int hi,
               float& li, f32x16& o0, f32x16& o1) {
  float s0 = 0.f, s1 = 0.f, s2 = 0.f, s3 = 0.f;
#pragma unroll
  for (int r = 0; r < 16; r++) {
    const float p0 = __builtin_amdgcn_exp2f(z0[r]);
    const float p1 = __builtin_amdgcn_exp2f(z1[r]);
    z0[r] = p0; z1[r] = p1;
    if ((r & 3) == 0) { s0 += p0; s0 += p1; }
    else if ((r & 3) == 1) { s1 += p0; s1 += p1; }
    else if ((r & 3) == 2) { s2 += p0; s2 += p1; }
    else { s3 += p0; s3 += p1; }
  }
  li += (s0 + s1) + (s2 + s3);
  __builtin_amdgcn_s_setprio(1);
  pv_half(z0, 0, Vsb, l31, hi, o0, o1);
  pv_half(z1, 2, Vsb, l31, hi, o0, o1);
  __builtin_amdgcn_s_setprio(0);
}

// ---- flash attention: QBLK=128, 4 waves. T15 deferred softmax (R15: 49.4->46.7).
// V triple-buffered, K double-buffered. XCD swizzle, T5, T12. ----
__global__ __launch_bounds__(256, 2) void k_attn(const u16* __restrict__ Qb,
                                                 const u16* __restrict__ Kb,
                                                 const u16* __restrict__ Vt,
                                                 u16* __restrict__ attnB) {
  __shared__ u16 Ks[2][64][72];  // [buf][key][dh]       18.4KB
  __shared__ u16 Vs[3][64][72];  // [buf][dh][key_local] 27.6KB
  __shared__ u16 Pl[4][32][72];  // epilogue-only (O staging) 18.4KB
  const int tid = threadIdx.x;
  const int lane = tid & 63, wave = tid >> 6;
  const int l31 = lane & 31, hi = lane >> 5;
  // XCD swizzle: nwg = 512, chunk = 64 (4 bh of 16 q-blocks per XCD)
  const int bid0 = blockIdx.x + 16 * blockIdx.y;
  const int bid = (bid0 & 7) * 64 + (bid0 >> 3);
  const int bh = bid >> 4;
  const int q0 = (bid & 15) * 128;
  const u16* Qh = Qb + (size_t)bh * S * 64;
  const u16* Kh = Kb + (size_t)bh * S * 64;
  const u16* Vh = Vt + (size_t)bh * 64 * S;
  const int qrow = q0 + wave * 32 + l31;
  bf16x8 qf[4];  // Q (pre-scaled by SCQ) as B-operand: n = lane&31 = q
#pragma unroll
  for (int f = 0; f < 4; f++)
    qf[f] = *reinterpret_cast<const bf16x8*>(&Qh[(size_t)qrow * 64 + f * 16 + hi * 8]);

  const int r0 = tid >> 3, c0 = (tid & 7) * 8;  // staging: 8 lanes x 16B per 128B row

  float li = 0.f;
  f32x16 o0, o1;  // O d-tiles: d = dt*32 + (reg&3)+8*(reg>>2)+4*hi
#pragma unroll
  for (int r = 0; r < 16; r++) { o0[r] = 0.f; o1[r] = 0.f; }
  f32x16 zE0, zE1, zO0, zO1;  // even/odd-iter score sets (named; no arrays)

  // prologue: tile 0 -> regs
  uint4 pk0 = *reinterpret_cast<const uint4*>(&Kh[(size_t)r0 * 64 + c0]);
  uint4 pk1 = *reinterpret_cast<const uint4*>(&Kh[(size_t)(r0 + 32) * 64 + c0]);
  uint4 pv0 = *reinterpret_cast<const uint4*>(&Vh[(size_t)r0 * S + c0]);
  uint4 pv1 = *reinterpret_cast<const uint4*>(&Vh[(size_t)(r0 + 32) * S + c0]);

  constexpr int NT = S / 64;  // 32 (even)

#define ATTN_STEP(KB, ZC0, ZC1, ZP0, ZP1, DO_CONS)                                \
  {                                                                               \
    const int cur_ = (KB) & 1, vb_ = (KB) % 3;                                    \
    *reinterpret_cast<uint4*>(&Ks[cur_][r0][c0]) = pk0;                           \
    *reinterpret_cast<uint4*>(&Ks[cur_][r0 + 32][c0]) = pk1;                      \
    *reinterpret_cast<uint4*>(&Vs[vb_][r0][c0]) = pv0;                            \
    *reinterpret_cast<uint4*>(&Vs[vb_][r0 + 32][c0]) = pv1;                       \
    if ((KB) + 1 < NT) {                                                          \
      const u16* Kn_ = Kh + (size_t)((KB) + 1) * 64 * 64;                         \
      const u16* Vn_ = Vh + (size_t)((KB) + 1) * 64;                              \
      pk0 = *reinterpret_cast<const uint4*>(&Kn_[(size_t)r0 * 64 + c0]);          \
      pk1 = *reinterpret_cast<const uint4*>(&Kn_[(size_t)(r0 + 32) * 64 + c0]);   \
      pv0 = *reinterpret_cast<const uint4*>(&Vn_[(size_t)r0 * S + c0]);           \
      pv1 = *reinterpret_cast<const uint4*>(&Vn_[(size_t)(r0 + 32) * S + c0]);    \
    }                                                                             \
    __syncthreads();                                                              \
    qk_produce(ZC0, ZC1, Ks[cur_], qf, l31, hi);                                  \
    if (DO_CONS) sm_pv(ZP0, ZP1, Vs[((KB) + 2) % 3], l31, hi, li, o0, o1);        \
  }

  for (int p = 0; p < NT / 2; p++) {
    ATTN_STEP(2 * p,     zE0, zE1, zO0, zO1, p > 0);
    ATTN_STEP(2 * p + 1, zO0, zO1, zE0, zE1, true);
  }
  // epilogue: consume last tile (NT-1, odd -> zO), V in buf (NT-1)%3
  sm_pv(zO0, zO1, Vs[(NT - 1) % 3], l31, hi, li, o0, o1);
#undef ATTN_STEP

  li += __shfl_xor(li, 32);
  const float inv = 1.f / li;
  // O -> Pl[q][d] (wave-private), then coalesced store
#pragma unroll
  for (int dt = 0; dt < 2; dt++) {
    const f32x16& od = dt ? o1 : o0;
#pragma unroll
    for (int g = 0; g < 4; g++) {
      uint2 ow;
      ow.x = pk2(od[g * 4 + 0] * inv, od[g * 4 + 1] * inv);
      ow.y = pk2(od[g * 4 + 2] * inv, od[g * 4 + 3] * inv);
      *reinterpret_cast<uint2*>(&Pl[wave][l31][dt * 32 + g * 8 + hi * 4]) = ow;
    }
  }
  const int b = bh >> 4, h = bh & 15;
  const int mbase = b * S + q0 + wave * 32;
  const int qr = lane >> 1, ch = (lane & 1) * 32;
  u16* dst = &attnB[(size_t)(mbase + qr) * D + h * 64 + ch];
#pragma unroll
  for (int c = 0; c < 4; c++)
    reinterpret_cast<uint4*>(dst)[c] = *reinterpret_cast<const uint4*>(&Pl[wave][qr][ch + c * 8]);
}

extern "C" void kernel_launch(void* const* d_in, const int* in_sizes, int n_in,
                              void* d_out, int out_size, void* d_ws, size_t ws_size,
                              hipStream_t stream) {
  const float* x = (const float*)d_in[0];
  const float* Wqkv = (const float*)d_in[1];
  const float* bqkv = (const float*)d_in[2];
  const float* Wout = (const float*)d_in[3];
  const float* bout = (const float*)d_in[4];
  float* out = (float*)d_out;

  char* p = (char*)d_ws;
  u16* WoutT = (u16*)p; p += (size_t)1024 * 1024 * 2;     // 2MB  (live thru gemm2)
  u16* attnB = (u16*)p; p += (size_t)4096 * 1024 * 2;     // 8MB  (live thru gemm2)
  u16* Xb = (u16*)p;    p += (size_t)4096 * 1024 * 2;     // 8MB  (dead after gemm0)
  u16* WqkvT = (u16*)p; p += (size_t)3072 * 1024 * 2;     // 6MB  (dead after gemm0)
  u16* Vt = (u16*)p;    p += (size_t)32 * 64 * 2048 * 2;  // 8MB  (dead after attn)
  u16* Qb = (u16*)p;    p += (size_t)32 * 2048 * 64 * 2;  // 8MB  (dead after attn)
  u16* Kb = (u16*)p;    p += (size_t)32 * 2048 * 64 * 2;  // 8MB  (dead after attn)

  k_prep<<<4096 + 3072 + 1024, 256, 0, stream>>>(x, Xb, Wqkv, WqkvT, Wout, WoutT);
  k_gemm0<<<dim3(3072 / 128, 4096 / 128), 256, 0, stream>>>(
      Xb, WqkvT, bqkv, 4096, 3072, 1024, Qb, Kb, Vt);
  k_attn<<<dim3(2048 / 128, 32), 256, 0, stream>>>(Qb, Kb, Vt, attnB);
  k_gemm2<<<dim3(1024 / 64, 4096 / 128), 256, 0, stream>>>(attnB, WoutT, bout, out);
}